// Round 15
// baseline (502.240 us; speedup 1.0000x reference)
//
#include <hip/hip_runtime.h>

#define NN 100000
#define NE 1600000
#define HID 64
#define NT (NN / 16)           // 16-node MFMA tiles
#define NL 3
#define BN_EPS 1e-5f
#define BSH 7
#define BNODES 128
#define NB 782                 // ceil(NN / BNODES)
#define GP 16                  // global counter pad (ints) -> 64 B/line
#define BIN_CHUNK 8192
#define BIN_GRID ((NE + BIN_CHUNK - 1) / BIN_CHUNK)
#define GBLK 3125              // gather: 12500 waves x 8 nodes = 100000
#define DCHUNK 8192
#define DGRID ((NN + DCHUNK - 1) / DCHUNK)

typedef __attribute__((ext_vector_type(8))) short short8;
typedef __attribute__((ext_vector_type(4))) float f32x4;

__device__ __forceinline__ float bf2f(unsigned short u) {
    union { unsigned int i; float f; } v; v.i = ((unsigned int)u) << 16; return v.f;
}
__device__ __forceinline__ unsigned short f2bf(float f) {
    union { float f; unsigned int i; } v; v.f = f;
    unsigned int r = v.i + 0x7FFFu + ((v.i >> 16) & 1u);   // RNE
    return (unsigned short)(r >> 16);
}
__device__ __forceinline__ float lof(uint r) {
    union { uint u; float f; } v; v.u = r << 16; return v.f;
}
__device__ __forceinline__ float hif(uint r) {
    union { uint u; float f; } v; v.u = r & 0xFFFF0000u; return v.f;
}
__device__ __forceinline__ float2 cvt2(uint u) {
    return make_float2(lof(u), hif(u));     // {lo bf16, hi bf16} as f32 pair
}

// ---------------- input convert x f32 -> bf16 row-major ----------------
__global__ void k_conv(const float* __restrict__ x, ushort* __restrict__ xb) {
    int i = blockIdx.x * blockDim.x + threadIdx.x;   // over NN*HID/4
    float4 v = ((const float4*)x)[i];
    ushort4 o;
    o.x = f2bf(v.x); o.y = f2bf(v.y); o.z = f2bf(v.z); o.w = f2bf(v.w);
    ((ushort4*)xb)[i] = o;
}

// ---------------- pack W1/W2 into hi/lo bf16 MFMA fragments ----------------
__global__ void k_wpack(const float* __restrict__ W1, const float* __restrict__ W2,
                        ushort* __restrict__ wf) {
    int s = blockIdx.x, l = threadIdx.x;
    int layer = s >> 2, kind = s & 3;
    const float* W = ((kind < 2) ? W1 : W2) + (size_t)layer * HID * HID;
    ushort* o = wf + (size_t)s * 4096;
    for (int kh = 0; kh < 2; ++kh)
        for (int t = 0; t < 4; ++t)
            for (int j = 0; j < 8; ++j) {
                int k = kh * 32 + (l >> 4) * 8 + j;
                int n = t * 16 + (l & 15);
                float f = W[k * HID + n];
                ushort hi = f2bf(f);
                o[((kh * 4 + t) * 64 + l) * 8 + j] =
                    (kind & 1) ? f2bf(f - bf2f(hi)) : hi;
            }
}

// ------- bucket histogram: 1024 thr, int4 batch; saves per-block counts -------
__global__ __launch_bounds__(1024) void k_histB(const int* __restrict__ dst,
                                                int* __restrict__ ghist,
                                                int* __restrict__ pcnt) {
    __shared__ int lh[NB];
    int tid = threadIdx.x;
    for (int i = tid; i < NB; i += 1024) lh[i] = 0;
    __syncthreads();
    int base = blockIdx.x * BIN_CHUNK;
    int end = min(base + BIN_CHUNK, NE);
    for (int e = base + tid * 4; e + 3 < end; e += 4096) {
        int4 d = *(const int4*)(dst + e);
        atomicAdd(&lh[d.x >> BSH], 1);
        atomicAdd(&lh[d.y >> BSH], 1);
        atomicAdd(&lh[d.z >> BSH], 1);
        atomicAdd(&lh[d.w >> BSH], 1);
    }
    __syncthreads();
    int* prow = pcnt + (size_t)blockIdx.x * NB;
    for (int i = tid; i < NB; i += 1024) {
        int c = lh[i];
        prow[i] = c;                                  // coalesced save for binB
        if (c) atomicAdd(&ghist[i * GP], c);
    }
}

// ---------------- bucket scan (one block, NB <= 1024) ----------------
__global__ void k_scanB(const int* __restrict__ ghist, int* __restrict__ boffB,
                        int* __restrict__ gcur) {
    __shared__ int t[1024];
    int tid = threadIdx.x;
    int v = (tid < NB) ? ghist[tid * GP] : 0;
    t[tid] = v;
    __syncthreads();
    for (int d = 1; d < 1024; d <<= 1) {
        int u = (tid >= d) ? t[tid - d] : 0;
        __syncthreads();
        t[tid] += u;
        __syncthreads();
    }
    if (tid < NB) { int ex = t[tid] - v; boffB[tid] = ex; gcur[tid * GP] = ex; }
    if (tid == 0) boffB[NB] = NE;
}

// ------- binning: reuses pcnt (no re-hist), bulk reserve, 4-edge batch -------
__global__ __launch_bounds__(1024) void k_binB(const int* __restrict__ ei,
                                               const float* __restrict__ att,
                                               const int* __restrict__ pcnt,
                                               int* __restrict__ gcur,
                                               int2* __restrict__ evb) {
    __shared__ int lh[NB];
    int tid = threadIdx.x;
    const int* prow = pcnt + (size_t)blockIdx.x * NB;
    for (int i = tid; i < NB; i += 1024) {
        int c = prow[i];
        lh[i] = c ? atomicAdd(&gcur[i * GP], c) : 0;   // lh becomes running cursor
    }
    __syncthreads();
    int base = blockIdx.x * BIN_CHUNK;
    int end = min(base + BIN_CHUNK, NE);
    for (int e = base + tid * 4; e + 3 < end; e += 4096) {
        int4 s = *(const int4*)(ei + e);
        int4 d = *(const int4*)(ei + NE + e);
        float4 a = *(const float4*)(att + e);
        int p0 = atomicAdd(&lh[d.x >> BSH], 1);
        int p1 = atomicAdd(&lh[d.y >> BSH], 1);
        int p2 = atomicAdd(&lh[d.z >> BSH], 1);
        int p3 = atomicAdd(&lh[d.w >> BSH], 1);
        evb[p0] = make_int2(s.x | ((d.x & (BNODES - 1)) << 17), __float_as_int(a.x));
        evb[p1] = make_int2(s.y | ((d.y & (BNODES - 1)) << 17), __float_as_int(a.y));
        evb[p2] = make_int2(s.z | ((d.z & (BNODES - 1)) << 17), __float_as_int(a.z));
        evb[p3] = make_int2(s.w | ((d.w & (BNODES - 1)) << 17), __float_as_int(a.w));
    }
}

// ------- pass 2: per-bucket CSR placement; also feeds degree histogram -------
__global__ __launch_bounds__(256) void k_scatter2(const int2* __restrict__ evb,
                                                  const int* __restrict__ boffB,
                                                  int* __restrict__ offs,
                                                  uint* __restrict__ evc,
                                                  int* __restrict__ dh) {
    __shared__ int h[BNODES];
    __shared__ int cur[BNODES];
    int tid = threadIdx.x;
    int b = blockIdx.x;
    int node0 = b << BSH;
    int nvalid = min(BNODES, NN - node0);
    int e0 = boffB[b], e1 = boffB[b + 1];
    if (tid < BNODES) h[tid] = 0;
    __syncthreads();
    for (int e = e0 + tid * 2; e < e1; e += 512) {
        int2 r0 = evb[e];
        int v1 = (e + 1 < e1);
        int2 r1 = evb[v1 ? e + 1 : e];
        atomicAdd(&h[r0.x >> 17], 1);
        if (v1) atomicAdd(&h[r1.x >> 17], 1);
    }
    __syncthreads();
    int v = (tid < BNODES) ? h[tid] : 0;
    if (tid < nvalid) atomicAdd(&dh[min(v, 255) * GP], 1);   // degree hist (was k_dhist)
    for (int d = 1; d < BNODES; d <<= 1) {
        int u = (tid >= d && tid < BNODES) ? h[tid - d] : 0;
        __syncthreads();
        if (tid < BNODES) h[tid] += u;
        __syncthreads();
    }
    if (tid < BNODES) {
        int start = e0 + h[tid] - v;
        cur[tid] = start;
        if (tid < nvalid) offs[node0 + tid] = start;
    }
    if (b == NB - 1 && tid == 0) offs[NN] = NE;
    __syncthreads();
    for (int e = e0 + tid * 2; e < e1; e += 512) {
        int2 r0 = evb[e];
        int v1 = (e + 1 < e1);
        int2 r1 = evb[v1 ? e + 1 : e];
        int p0 = atomicAdd(&cur[r0.x >> 17], 1);
        int p1 = v1 ? atomicAdd(&cur[r1.x >> 17], 1) : 0;
        uint a0 = (uint)(__int_as_float(r0.y) * 32767.0f + 0.5f);
        evc[p0] = ((uint)r0.x & 0x1FFFFu) | (a0 << 17);
        if (v1) {
            uint a1 = (uint)(__int_as_float(r1.y) * 32767.0f + 0.5f);
            evc[p1] = ((uint)r1.x & 0x1FFFFu) | (a1 << 17);
        }
    }
}

// ---------------- degree sort: scan -> place ----------------
__global__ void k_dscan(const int* __restrict__ dh, int* __restrict__ dcur) {
    __shared__ int t[256];
    int tid = threadIdx.x;
    int v = dh[tid * GP];
    t[tid] = v;
    __syncthreads();
    for (int d = 1; d < 256; d <<= 1) {
        int u = (tid >= d) ? t[tid - d] : 0;
        __syncthreads();
        t[tid] += u;
        __syncthreads();
    }
    dcur[tid * GP] = t[tid] - v;
}

__global__ __launch_bounds__(1024) void k_dplace(const int* __restrict__ offs,
                                                 int* __restrict__ dcur,
                                                 int* __restrict__ perm) {
    __shared__ int lh[256];
    __shared__ int lbase[256];
    int tid = threadIdx.x;
    if (tid < 256) lh[tid] = 0;
    __syncthreads();
    int lo = blockIdx.x * DCHUNK, hi = min(lo + DCHUNK, NN);
    int mybin[8], myrk[8];
#pragma unroll 8
    for (int u = 0; u < 8; ++u) {
        int i = lo + u * 1024 + tid;
        if (i < hi) {
            int b = min(offs[i + 1] - offs[i], 255);
            mybin[u] = b;
            myrk[u] = atomicAdd(&lh[b], 1);
        } else mybin[u] = -1;
    }
    __syncthreads();
    if (tid < 256) {
        int c = lh[tid];
        lbase[tid] = c ? atomicAdd(&dcur[tid * GP], c) : 0;
    }
    __syncthreads();
#pragma unroll 8
    for (int u = 0; u < 8; ++u) {
        int i = lo + u * 1024 + tid;
        if (mybin[u] >= 0) perm[lbase[mybin[u]] + myrk[u]] = i;
    }
}

// ------- gather: 8 nodes/wave, uint4 rows, float2 packed accum, 24 waves/CU -------
__global__ __launch_bounds__(256, 6) void k_gather(const ushort* __restrict__ xb,
                                                   const int* __restrict__ offs,
                                                   const uint* __restrict__ evc,
                                                   const int* __restrict__ perm,
                                                   ushort* __restrict__ agg) {
    int tid = threadIdx.x;
    int wid = blockIdx.x * 4 + (tid >> 6);
    int lane = tid & 63;
    int g = lane >> 3, k = lane & 7;
    const uint4* xq4 = (const uint4*)xb;
    uint4* aq4 = (uint4*)agg;
    int node = perm[wid * 8 + g];
    int e0 = offs[node], e1 = offs[node + 1];
    int deg = e1 - e0;
    uint4 s4 = xq4[(size_t)node * 8 + k];                 // self row (+x, eps=0)
    float2 A0 = cvt2(s4.x), A1 = cvt2(s4.y), A2 = cvt2(s4.z), A3 = cvt2(s4.w);
    int maxd = deg;                                        // max degree over 8 groups
    maxd = max(maxd, __shfl_xor(maxd, 8, 64));
    maxd = max(maxd, __shfl_xor(maxd, 16, 64));
    maxd = max(maxd, __shfl_xor(maxd, 32, 64));
    for (int base = 0; base < maxd; base += 8) {
        uint ew = evc[min(e0 + base + k, NE - 1)];        // 8 metadata/group, batched
#pragma unroll 8
        for (int j = 0; j < 8; ++j) {
            uint w = (uint)__builtin_amdgcn_ds_bpermute((g * 8 + j) << 2, (int)ew);
            float a = (base + j < deg) ? (float)(w >> 17) * (1.0f / 32767.0f) : 0.f;
            float2 av = make_float2(a, a);
            uint4 r = xq4[(size_t)(w & 0x1FFFF) * 8 + k]; // 128 B row, 8 lanes
            A0 += cvt2(r.x) * av;                          // v_pk_fma_f32
            A1 += cvt2(r.y) * av;
            A2 += cvt2(r.z) * av;
            A3 += cvt2(r.w) * av;
        }
    }
    uint4 o;
    o.x = ((uint)f2bf(A0.x)) | (((uint)f2bf(A0.y)) << 16);
    o.y = ((uint)f2bf(A1.x)) | (((uint)f2bf(A1.y)) << 16);
    o.z = ((uint)f2bf(A2.x)) | (((uint)f2bf(A2.y)) << 16);
    o.w = ((uint)f2bf(A3.x)) | (((uint)f2bf(A3.y)) << 16);
    aq4[(size_t)node * 8 + k] = o;
}

// ------- mlp1 (MFMA, C^T): h = agg @ W1 + b1, BN stats; row-major -------
__global__ __launch_bounds__(256, 2) void k_mlp1(const ushort* __restrict__ aggc,
                                                 const ushort* __restrict__ wfb,
                                                 const float* __restrict__ b1,
                                                 ushort* __restrict__ h,
                                                 float* __restrict__ stats) {
    __shared__ float red1[4][64], red2[4][64];
    int tid = threadIdx.x, wv = tid >> 6, l = tid & 63;
    int lg = l >> 4, lc = l & 15;
    short8 bhi[2][4], blo[2][4];
#pragma unroll
    for (int kh = 0; kh < 2; ++kh)
#pragma unroll
        for (int t = 0; t < 4; ++t) {
            bhi[kh][t] = *(const short8*)(wfb + ((kh * 4 + t) * 64 + l) * 8);
            blo[kh][t] = *(const short8*)(wfb + 4096 + ((kh * 4 + t) * 64 + l) * 8);
        }
    f32x4 bias4[4];
#pragma unroll
    for (int t = 0; t < 4; ++t) {
        float4 bv = *(const float4*)(b1 + t * 16 + lg * 4);
        bias4[t] = (f32x4){bv.x, bv.y, bv.z, bv.w};
    }
    float s1[16], s2[16];
#pragma unroll
    for (int i = 0; i < 16; ++i) { s1[i] = 0.f; s2[i] = 0.f; }
    int gw = blockIdx.x * 4 + wv, nw = gridDim.x * 4;
    for (int tile = gw; tile < NT; tile += nw) {
        int node = tile * 16 + lc;
        const ushort* ap = aggc + (size_t)node * HID + lg * 8;
        short8 a0 = *(const short8*)ap;             // k = 0..31
        short8 a1 = *(const short8*)(ap + 32);      // k = 32..63
        f32x4 acc[4];
#pragma unroll
        for (int t = 0; t < 4; ++t) {
            acc[t] = bias4[t];
            acc[t] = __builtin_amdgcn_mfma_f32_16x16x32_bf16(bhi[0][t], a0, acc[t], 0, 0, 0);
            acc[t] = __builtin_amdgcn_mfma_f32_16x16x32_bf16(bhi[1][t], a1, acc[t], 0, 0, 0);
            acc[t] = __builtin_amdgcn_mfma_f32_16x16x32_bf16(blo[0][t], a0, acc[t], 0, 0, 0);
            acc[t] = __builtin_amdgcn_mfma_f32_16x16x32_bf16(blo[1][t], a1, acc[t], 0, 0, 0);
        }
#pragma unroll
        for (int t = 0; t < 4; ++t) {
            ushort4 o;
            float d0 = acc[t][0], d1 = acc[t][1], d2 = acc[t][2], d3 = acc[t][3];
            s1[t * 4 + 0] += d0; s2[t * 4 + 0] += d0 * d0;
            s1[t * 4 + 1] += d1; s2[t * 4 + 1] += d1 * d1;
            s1[t * 4 + 2] += d2; s2[t * 4 + 2] += d2 * d2;
            s1[t * 4 + 3] += d3; s2[t * 4 + 3] += d3 * d3;
            o.x = f2bf(d0); o.y = f2bf(d1); o.z = f2bf(d2); o.w = f2bf(d3);
            *(ushort4*)(h + (size_t)node * HID + t * 16 + lg * 4) = o;
        }
    }
#pragma unroll
    for (int i = 0; i < 16; ++i) {
        s1[i] += __shfl_xor(s1[i], 1, 64); s1[i] += __shfl_xor(s1[i], 2, 64);
        s1[i] += __shfl_xor(s1[i], 4, 64); s1[i] += __shfl_xor(s1[i], 8, 64);
        s2[i] += __shfl_xor(s2[i], 1, 64); s2[i] += __shfl_xor(s2[i], 2, 64);
        s2[i] += __shfl_xor(s2[i], 4, 64); s2[i] += __shfl_xor(s2[i], 8, 64);
    }
    if (lc == 0) {
#pragma unroll
        for (int t = 0; t < 4; ++t)
#pragma unroll
            for (int r = 0; r < 4; ++r) {
                red1[wv][t * 16 + lg * 4 + r] = s1[t * 4 + r];
                red2[wv][t * 16 + lg * 4 + r] = s2[t * 4 + r];
            }
    }
    __syncthreads();
    if (tid < 64)
        atomicAdd(&stats[tid], red1[0][tid] + red1[1][tid] + red1[2][tid] + red1[3][tid]);
    else if (tid < 128) {
        int c = tid - 64;
        atomicAdd(&stats[HID + c], red2[0][c] + red2[1][c] + red2[2][c] + red2[3][c]);
    }
}

// ------- mlp2 (MFMA, C^T): BN -> ReLU -> @W2+b2 -> ReLU; row-major -------
__global__ __launch_bounds__(256, 2) void k_mlp2(const ushort* __restrict__ wfb,
                                                 const float* __restrict__ b2,
                                                 const float* __restrict__ gamma,
                                                 const float* __restrict__ beta,
                                                 const float* __restrict__ stats,
                                                 const ushort* __restrict__ h,
                                                 ushort* __restrict__ xb_out,
                                                 float* __restrict__ f_out,
                                                 int write_f32) {
    int tid = threadIdx.x, wv = tid >> 6, l = tid & 63;
    int lg = l >> 4, lc = l & 15;
    short8 bhi[2][4], blo[2][4];
#pragma unroll
    for (int kh = 0; kh < 2; ++kh)
#pragma unroll
        for (int t = 0; t < 4; ++t) {
            bhi[kh][t] = *(const short8*)(wfb + 8192 + ((kh * 4 + t) * 64 + l) * 8);
            blo[kh][t] = *(const short8*)(wfb + 12288 + ((kh * 4 + t) * 64 + l) * 8);
        }
    f32x4 bias4[4];
#pragma unroll
    for (int t = 0; t < 4; ++t) {
        float4 bv = *(const float4*)(b2 + t * 16 + lg * 4);
        bias4[t] = (f32x4){bv.x, bv.y, bv.z, bv.w};
    }
    float aCk[2][8], bCk[2][8];
#pragma unroll
    for (int kh = 0; kh < 2; ++kh)
#pragma unroll
        for (int j = 0; j < 8; ++j) {
            int k = kh * 32 + lg * 8 + j;
            float mu = stats[k] * (1.0f / NN);
            float var = fmaxf(stats[HID + k] * (1.0f / NN) - mu * mu, 0.f);
            float aC = gamma[k] * rsqrtf(var + BN_EPS);
            aCk[kh][j] = aC;
            bCk[kh][j] = beta[k] - mu * aC;
        }
    int gw = blockIdx.x * 4 + wv, nw = gridDim.x * 4;
    for (int tile = gw; tile < NT; tile += nw) {
        int node = tile * 16 + lc;
        const ushort* hp = h + (size_t)node * HID + lg * 8;
        short8 a0r = *(const short8*)hp;
        short8 a1r = *(const short8*)(hp + 32);
        short8 a0, a1;
#pragma unroll
        for (int j = 0; j < 8; ++j) {
            float v0 = fmaxf(aCk[0][j] * bf2f((ushort)a0r[j]) + bCk[0][j], 0.f);
            float v1 = fmaxf(aCk[1][j] * bf2f((ushort)a1r[j]) + bCk[1][j], 0.f);
            a0[j] = (short)f2bf(v0);
            a1[j] = (short)f2bf(v1);
        }
        f32x4 acc[4];
#pragma unroll
        for (int t = 0; t < 4; ++t) {
            acc[t] = bias4[t];
            acc[t] = __builtin_amdgcn_mfma_f32_16x16x32_bf16(bhi[0][t], a0, acc[t], 0, 0, 0);
            acc[t] = __builtin_amdgcn_mfma_f32_16x16x32_bf16(bhi[1][t], a1, acc[t], 0, 0, 0);
            acc[t] = __builtin_amdgcn_mfma_f32_16x16x32_bf16(blo[0][t], a0, acc[t], 0, 0, 0);
            acc[t] = __builtin_amdgcn_mfma_f32_16x16x32_bf16(blo[1][t], a1, acc[t], 0, 0, 0);
        }
        if (write_f32) {
#pragma unroll
            for (int t = 0; t < 4; ++t) {
                float4 o4;
                o4.x = fmaxf(acc[t][0], 0.f); o4.y = fmaxf(acc[t][1], 0.f);
                o4.z = fmaxf(acc[t][2], 0.f); o4.w = fmaxf(acc[t][3], 0.f);
                *(float4*)(f_out + (size_t)node * HID + t * 16 + lg * 4) = o4;
            }
        } else {
#pragma unroll
            for (int t = 0; t < 4; ++t) {
                ushort4 o;
                o.x = f2bf(fmaxf(acc[t][0], 0.f)); o.y = f2bf(fmaxf(acc[t][1], 0.f));
                o.z = f2bf(fmaxf(acc[t][2], 0.f)); o.w = f2bf(fmaxf(acc[t][3], 0.f));
                *(ushort4*)(xb_out + (size_t)node * HID + t * 16 + lg * 4) = o;
            }
        }
    }
}

extern "C" void kernel_launch(void* const* d_in, const int* in_sizes, int n_in,
                              void* d_out, int out_size, void* d_ws, size_t ws_size,
                              hipStream_t stream) {
    const float* x_in  = (const float*)d_in[0];
    const int*   ei    = (const int*)d_in[1];
    const float* att   = (const float*)d_in[2];
    const float* W1    = (const float*)d_in[3];
    const float* b1    = (const float*)d_in[4];
    const float* gamma = (const float*)d_in[5];
    const float* beta  = (const float*)d_in[6];
    const float* W2    = (const float*)d_in[7];
    const float* b2    = (const float*)d_in[8];
    float* out = (float*)d_out;

    char* ws = (char*)d_ws;
    size_t off = 0;
    auto alloc = [&](size_t bytes) -> void* {
        void* p = ws + off;
        off += (bytes + 255) & ~(size_t)255;
        return p;
    };
    ushort* xb    = (ushort*)alloc((size_t)NN * HID * 2);   // row-major bf16 x
    ushort* aggb  = (ushort*)alloc((size_t)NN * HID * 2);
    ushort* hb    = (ushort*)alloc((size_t)NN * HID * 2);
    ushort* wf    = (ushort*)alloc((size_t)12 * 4096 * 2);  // W fragments hi/lo
    int*    ghist = (int*)alloc((size_t)NB * GP * 4);
    int*    boffB = (int*)alloc((size_t)(NB + 1) * 4);
    int*    gcur  = (int*)alloc((size_t)NB * GP * 4);
    int*    pcnt  = (int*)alloc((size_t)BIN_GRID * NB * 4); // per-block bucket counts
    int*    offs  = (int*)alloc((size_t)(NN + 1) * 4);
    int2*   evb   = (int2*)alloc((size_t)NE * 8);
    uint*   evc   = (uint*)alloc((size_t)NE * 4);           // src | att15<<17
    int*    dh    = (int*)alloc((size_t)256 * GP * 4);
    int*    dcur  = (int*)alloc((size_t)256 * GP * 4);
    int*    perm  = (int*)alloc((size_t)NN * 4);
    float*  stats = (float*)alloc(NL * 128 * 4);

    hipMemsetAsync(ghist, 0, (size_t)NB * GP * 4, stream);
    hipMemsetAsync(dh, 0, (size_t)256 * GP * 4, stream);
    hipMemsetAsync(stats, 0, NL * 128 * 4, stream);

    k_conv<<<(NN * HID / 4 + 255) / 256, 256, 0, stream>>>(x_in, xb);
    k_wpack<<<12, 64, 0, stream>>>(W1, W2, wf);
    k_histB<<<BIN_GRID, 1024, 0, stream>>>(ei + NE, ghist, pcnt);
    k_scanB<<<1, 1024, 0, stream>>>(ghist, boffB, gcur);
    k_binB<<<BIN_GRID, 1024, 0, stream>>>(ei, att, pcnt, gcur, evb);
    k_scatter2<<<NB, 256, 0, stream>>>(evb, boffB, offs, evc, dh);
    k_dscan<<<1, 256, 0, stream>>>(dh, dcur);
    k_dplace<<<DGRID, 1024, 0, stream>>>(offs, dcur, perm);

    for (int l = 0; l < NL; ++l) {
        const ushort* wfb = wf + (size_t)l * 4 * 4096;
        k_gather<<<GBLK, 256, 0, stream>>>(xb, offs, evc, perm, aggb);
        k_mlp1<<<1024, 256, 0, stream>>>(aggb, wfb, b1 + l * HID, hb, stats + l * 128);
        k_mlp2<<<1024, 256, 0, stream>>>(wfb, b2 + l * HID,
                                         gamma + l * HID, beta + l * HID,
                                         stats + l * 128, hb,
                                         xb, out, (l == NL - 1) ? 1 : 0);
    }
}

// Round 16
// 345.805 us; speedup vs baseline: 1.4524x; 1.4524x over previous
//
#include <hip/hip_runtime.h>

#define NN 100000
#define NE 1600000
#define HID 64
#define NT (NN / 16)           // 16-node MFMA tiles
#define NL 3
#define BN_EPS 1e-5f
#define BSH 7
#define BNODES 128
#define NB 782                 // ceil(NN / BNODES)
#define GP 16                  // global counter pad (ints) -> 64 B/line
#define BIN_CHUNK 8192
#define BIN_GRID ((NE + BIN_CHUNK - 1) / BIN_CHUNK)
#define GBLK 3125              // gather: 12500 waves x 8 nodes = 100000
#define DCHUNK 8192
#define DGRID ((NN + DCHUNK - 1) / DCHUNK)

typedef __attribute__((ext_vector_type(8))) short short8;
typedef __attribute__((ext_vector_type(4))) float f32x4;

__device__ __forceinline__ float bf2f(unsigned short u) {
    union { unsigned int i; float f; } v; v.i = ((unsigned int)u) << 16; return v.f;
}
__device__ __forceinline__ unsigned short f2bf(float f) {
    union { float f; unsigned int i; } v; v.f = f;
    unsigned int r = v.i + 0x7FFFu + ((v.i >> 16) & 1u);   // RNE
    return (unsigned short)(r >> 16);
}
__device__ __forceinline__ float lof(uint r) {
    union { uint u; float f; } v; v.u = r << 16; return v.f;
}
__device__ __forceinline__ float hif(uint r) {
    union { uint u; float f; } v; v.u = r & 0xFFFF0000u; return v.f;
}
__device__ __forceinline__ float2 cvt2(uint u) {
    return make_float2(lof(u), hif(u));     // {lo bf16, hi bf16} as f32 pair
}

// ---------------- input convert x f32 -> bf16 row-major ----------------
__global__ void k_conv(const float* __restrict__ x, ushort* __restrict__ xb) {
    int i = blockIdx.x * blockDim.x + threadIdx.x;   // over NN*HID/4
    float4 v = ((const float4*)x)[i];
    ushort4 o;
    o.x = f2bf(v.x); o.y = f2bf(v.y); o.z = f2bf(v.z); o.w = f2bf(v.w);
    ((ushort4*)xb)[i] = o;
}

// ---------------- pack W1/W2 into hi/lo bf16 MFMA fragments ----------------
__global__ void k_wpack(const float* __restrict__ W1, const float* __restrict__ W2,
                        ushort* __restrict__ wf) {
    int s = blockIdx.x, l = threadIdx.x;
    int layer = s >> 2, kind = s & 3;
    const float* W = ((kind < 2) ? W1 : W2) + (size_t)layer * HID * HID;
    ushort* o = wf + (size_t)s * 4096;
    for (int kh = 0; kh < 2; ++kh)
        for (int t = 0; t < 4; ++t)
            for (int j = 0; j < 8; ++j) {
                int k = kh * 32 + (l >> 4) * 8 + j;
                int n = t * 16 + (l & 15);
                float f = W[k * HID + n];
                ushort hi = f2bf(f);
                o[((kh * 4 + t) * 64 + l) * 8 + j] =
                    (kind & 1) ? f2bf(f - bf2f(hi)) : hi;
            }
}

// ------- bucket histogram: 1024 thr, int4 batch; saves per-block counts -------
__global__ __launch_bounds__(1024) void k_histB(const int* __restrict__ dst,
                                                int* __restrict__ ghist,
                                                int* __restrict__ pcnt) {
    __shared__ int lh[NB];
    int tid = threadIdx.x;
    for (int i = tid; i < NB; i += 1024) lh[i] = 0;
    __syncthreads();
    int base = blockIdx.x * BIN_CHUNK;
    int end = min(base + BIN_CHUNK, NE);
    for (int e = base + tid * 4; e + 3 < end; e += 4096) {
        int4 d = *(const int4*)(dst + e);
        atomicAdd(&lh[d.x >> BSH], 1);
        atomicAdd(&lh[d.y >> BSH], 1);
        atomicAdd(&lh[d.z >> BSH], 1);
        atomicAdd(&lh[d.w >> BSH], 1);
    }
    __syncthreads();
    int* prow = pcnt + (size_t)blockIdx.x * NB;
    for (int i = tid; i < NB; i += 1024) {
        int c = lh[i];
        prow[i] = c;                                  // coalesced save for binB
        if (c) atomicAdd(&ghist[i * GP], c);
    }
}

// ---------------- bucket scan (one block, NB <= 1024) ----------------
__global__ void k_scanB(const int* __restrict__ ghist, int* __restrict__ boffB,
                        int* __restrict__ gcur) {
    __shared__ int t[1024];
    int tid = threadIdx.x;
    int v = (tid < NB) ? ghist[tid * GP] : 0;
    t[tid] = v;
    __syncthreads();
    for (int d = 1; d < 1024; d <<= 1) {
        int u = (tid >= d) ? t[tid - d] : 0;
        __syncthreads();
        t[tid] += u;
        __syncthreads();
    }
    if (tid < NB) { int ex = t[tid] - v; boffB[tid] = ex; gcur[tid * GP] = ex; }
    if (tid == 0) boffB[NB] = NE;
}

// ------- binning: reuses pcnt (no re-hist), bulk reserve, 4-edge batch -------
__global__ __launch_bounds__(1024) void k_binB(const int* __restrict__ ei,
                                               const float* __restrict__ att,
                                               const int* __restrict__ pcnt,
                                               int* __restrict__ gcur,
                                               int2* __restrict__ evb) {
    __shared__ int lh[NB];
    int tid = threadIdx.x;
    const int* prow = pcnt + (size_t)blockIdx.x * NB;
    for (int i = tid; i < NB; i += 1024) {
        int c = prow[i];
        lh[i] = c ? atomicAdd(&gcur[i * GP], c) : 0;   // lh becomes running cursor
    }
    __syncthreads();
    int base = blockIdx.x * BIN_CHUNK;
    int end = min(base + BIN_CHUNK, NE);
    for (int e = base + tid * 4; e + 3 < end; e += 4096) {
        int4 s = *(const int4*)(ei + e);
        int4 d = *(const int4*)(ei + NE + e);
        float4 a = *(const float4*)(att + e);
        int p0 = atomicAdd(&lh[d.x >> BSH], 1);
        int p1 = atomicAdd(&lh[d.y >> BSH], 1);
        int p2 = atomicAdd(&lh[d.z >> BSH], 1);
        int p3 = atomicAdd(&lh[d.w >> BSH], 1);
        evb[p0] = make_int2(s.x | ((d.x & (BNODES - 1)) << 17), __float_as_int(a.x));
        evb[p1] = make_int2(s.y | ((d.y & (BNODES - 1)) << 17), __float_as_int(a.y));
        evb[p2] = make_int2(s.z | ((d.z & (BNODES - 1)) << 17), __float_as_int(a.z));
        evb[p3] = make_int2(s.w | ((d.w & (BNODES - 1)) << 17), __float_as_int(a.w));
    }
}

// ------- pass 2: per-bucket CSR placement; compressed 4 B records -------
__global__ __launch_bounds__(256) void k_scatter2(const int2* __restrict__ evb,
                                                  const int* __restrict__ boffB,
                                                  int* __restrict__ offs,
                                                  uint* __restrict__ evc) {
    __shared__ int h[BNODES];
    __shared__ int cur[BNODES];
    int tid = threadIdx.x;
    int b = blockIdx.x;
    int node0 = b << BSH;
    int nvalid = min(BNODES, NN - node0);
    int e0 = boffB[b], e1 = boffB[b + 1];
    if (tid < BNODES) h[tid] = 0;
    __syncthreads();
    for (int e = e0 + tid * 2; e < e1; e += 512) {
        int2 r0 = evb[e];
        int v1 = (e + 1 < e1);
        int2 r1 = evb[v1 ? e + 1 : e];
        atomicAdd(&h[r0.x >> 17], 1);
        if (v1) atomicAdd(&h[r1.x >> 17], 1);
    }
    __syncthreads();
    int v = (tid < BNODES) ? h[tid] : 0;
    for (int d = 1; d < BNODES; d <<= 1) {
        int u = (tid >= d && tid < BNODES) ? h[tid - d] : 0;
        __syncthreads();
        if (tid < BNODES) h[tid] += u;
        __syncthreads();
    }
    if (tid < BNODES) {
        int start = e0 + h[tid] - v;
        cur[tid] = start;
        if (tid < nvalid) offs[node0 + tid] = start;
    }
    if (b == NB - 1 && tid == 0) offs[NN] = NE;
    __syncthreads();
    for (int e = e0 + tid * 2; e < e1; e += 512) {
        int2 r0 = evb[e];
        int v1 = (e + 1 < e1);
        int2 r1 = evb[v1 ? e + 1 : e];
        int p0 = atomicAdd(&cur[r0.x >> 17], 1);
        int p1 = v1 ? atomicAdd(&cur[r1.x >> 17], 1) : 0;
        uint a0 = (uint)(__int_as_float(r0.y) * 32767.0f + 0.5f);
        evc[p0] = ((uint)r0.x & 0x1FFFFu) | (a0 << 17);
        if (v1) {
            uint a1 = (uint)(__int_as_float(r1.y) * 32767.0f + 0.5f);
            evc[p1] = ((uint)r1.x & 0x1FFFFu) | (a1 << 17);
        }
    }
}

// ---------------- degree sort: hist (LDS pre-aggregated) -> scan -> place ----------------
__global__ __launch_bounds__(1024) void k_dhist(const int* __restrict__ offs,
                                                int* __restrict__ dh) {
    __shared__ int lh[256];
    int tid = threadIdx.x;
    if (tid < 256) lh[tid] = 0;
    __syncthreads();
    int lo = blockIdx.x * DCHUNK, hi = min(lo + DCHUNK, NN);
    for (int i = lo + tid; i < hi; i += 1024)
        atomicAdd(&lh[min(offs[i + 1] - offs[i], 255)], 1);
    __syncthreads();
    if (tid < 256 && lh[tid]) atomicAdd(&dh[tid * GP], lh[tid]);
}

__global__ void k_dscan(const int* __restrict__ dh, int* __restrict__ dcur) {
    __shared__ int t[256];
    int tid = threadIdx.x;
    int v = dh[tid * GP];
    t[tid] = v;
    __syncthreads();
    for (int d = 1; d < 256; d <<= 1) {
        int u = (tid >= d) ? t[tid - d] : 0;
        __syncthreads();
        t[tid] += u;
        __syncthreads();
    }
    dcur[tid * GP] = t[tid] - v;
}

__global__ __launch_bounds__(1024) void k_dplace(const int* __restrict__ offs,
                                                 int* __restrict__ dcur,
                                                 int* __restrict__ perm) {
    __shared__ int lh[256];
    __shared__ int lbase[256];
    int tid = threadIdx.x;
    if (tid < 256) lh[tid] = 0;
    __syncthreads();
    int lo = blockIdx.x * DCHUNK, hi = min(lo + DCHUNK, NN);
    int mybin[8], myrk[8];
#pragma unroll 8
    for (int u = 0; u < 8; ++u) {
        int i = lo + u * 1024 + tid;
        if (i < hi) {
            int b = min(offs[i + 1] - offs[i], 255);
            mybin[u] = b;
            myrk[u] = atomicAdd(&lh[b], 1);
        } else mybin[u] = -1;
    }
    __syncthreads();
    if (tid < 256) {
        int c = lh[tid];
        lbase[tid] = c ? atomicAdd(&dcur[tid * GP], c) : 0;
    }
    __syncthreads();
#pragma unroll 8
    for (int u = 0; u < 8; ++u) {
        int i = lo + u * 1024 + tid;
        if (mybin[u] >= 0) perm[lbase[mybin[u]] + myrk[u]] = i;
    }
}

// ------- gather: 8 nodes/wave, uint4 rows, float2 packed accum, 24 waves/CU -------
__global__ __launch_bounds__(256, 6) void k_gather(const ushort* __restrict__ xb,
                                                   const int* __restrict__ offs,
                                                   const uint* __restrict__ evc,
                                                   const int* __restrict__ perm,
                                                   ushort* __restrict__ agg) {
    int tid = threadIdx.x;
    int wid = blockIdx.x * 4 + (tid >> 6);
    int lane = tid & 63;
    int g = lane >> 3, k = lane & 7;
    const uint4* xq4 = (const uint4*)xb;
    uint4* aq4 = (uint4*)agg;
    int node = perm[wid * 8 + g];
    int e0 = offs[node], e1 = offs[node + 1];
    int deg = e1 - e0;
    uint4 s4 = xq4[(size_t)node * 8 + k];                 // self row (+x, eps=0)
    float2 A0 = cvt2(s4.x), A1 = cvt2(s4.y), A2 = cvt2(s4.z), A3 = cvt2(s4.w);
    int maxd = deg;                                        // max degree over 8 groups
    maxd = max(maxd, __shfl_xor(maxd, 8, 64));
    maxd = max(maxd, __shfl_xor(maxd, 16, 64));
    maxd = max(maxd, __shfl_xor(maxd, 32, 64));
    for (int base = 0; base < maxd; base += 8) {
        uint ew = evc[min(e0 + base + k, NE - 1)];        // 8 metadata/group, batched
#pragma unroll 8
        for (int j = 0; j < 8; ++j) {
            uint w = (uint)__builtin_amdgcn_ds_bpermute((g * 8 + j) << 2, (int)ew);
            float a = (base + j < deg) ? (float)(w >> 17) * (1.0f / 32767.0f) : 0.f;
            float2 av = make_float2(a, a);
            uint4 r = xq4[(size_t)(w & 0x1FFFF) * 8 + k]; // 128 B row, 8 lanes
            A0 += cvt2(r.x) * av;                          // v_pk_fma_f32
            A1 += cvt2(r.y) * av;
            A2 += cvt2(r.z) * av;
            A3 += cvt2(r.w) * av;
        }
    }
    uint4 o;
    o.x = ((uint)f2bf(A0.x)) | (((uint)f2bf(A0.y)) << 16);
    o.y = ((uint)f2bf(A1.x)) | (((uint)f2bf(A1.y)) << 16);
    o.z = ((uint)f2bf(A2.x)) | (((uint)f2bf(A2.y)) << 16);
    o.w = ((uint)f2bf(A3.x)) | (((uint)f2bf(A3.y)) << 16);
    aq4[(size_t)node * 8 + k] = o;
}

// ------- mlp1 (MFMA, C^T): h = agg @ W1 + b1, BN stats; row-major -------
__global__ __launch_bounds__(256, 2) void k_mlp1(const ushort* __restrict__ aggc,
                                                 const ushort* __restrict__ wfb,
                                                 const float* __restrict__ b1,
                                                 ushort* __restrict__ h,
                                                 float* __restrict__ stats) {
    __shared__ float red1[4][64], red2[4][64];
    int tid = threadIdx.x, wv = tid >> 6, l = tid & 63;
    int lg = l >> 4, lc = l & 15;
    short8 bhi[2][4], blo[2][4];
#pragma unroll
    for (int kh = 0; kh < 2; ++kh)
#pragma unroll
        for (int t = 0; t < 4; ++t) {
            bhi[kh][t] = *(const short8*)(wfb + ((kh * 4 + t) * 64 + l) * 8);
            blo[kh][t] = *(const short8*)(wfb + 4096 + ((kh * 4 + t) * 64 + l) * 8);
        }
    f32x4 bias4[4];
#pragma unroll
    for (int t = 0; t < 4; ++t) {
        float4 bv = *(const float4*)(b1 + t * 16 + lg * 4);
        bias4[t] = (f32x4){bv.x, bv.y, bv.z, bv.w};
    }
    float s1[16], s2[16];
#pragma unroll
    for (int i = 0; i < 16; ++i) { s1[i] = 0.f; s2[i] = 0.f; }
    int gw = blockIdx.x * 4 + wv, nw = gridDim.x * 4;
    for (int tile = gw; tile < NT; tile += nw) {
        int node = tile * 16 + lc;
        const ushort* ap = aggc + (size_t)node * HID + lg * 8;
        short8 a0 = *(const short8*)ap;             // k = 0..31
        short8 a1 = *(const short8*)(ap + 32);      // k = 32..63
        f32x4 acc[4];
#pragma unroll
        for (int t = 0; t < 4; ++t) {
            acc[t] = bias4[t];
            acc[t] = __builtin_amdgcn_mfma_f32_16x16x32_bf16(bhi[0][t], a0, acc[t], 0, 0, 0);
            acc[t] = __builtin_amdgcn_mfma_f32_16x16x32_bf16(bhi[1][t], a1, acc[t], 0, 0, 0);
            acc[t] = __builtin_amdgcn_mfma_f32_16x16x32_bf16(blo[0][t], a0, acc[t], 0, 0, 0);
            acc[t] = __builtin_amdgcn_mfma_f32_16x16x32_bf16(blo[1][t], a1, acc[t], 0, 0, 0);
        }
#pragma unroll
        for (int t = 0; t < 4; ++t) {
            ushort4 o;
            float d0 = acc[t][0], d1 = acc[t][1], d2 = acc[t][2], d3 = acc[t][3];
            s1[t * 4 + 0] += d0; s2[t * 4 + 0] += d0 * d0;
            s1[t * 4 + 1] += d1; s2[t * 4 + 1] += d1 * d1;
            s1[t * 4 + 2] += d2; s2[t * 4 + 2] += d2 * d2;
            s1[t * 4 + 3] += d3; s2[t * 4 + 3] += d3 * d3;
            o.x = f2bf(d0); o.y = f2bf(d1); o.z = f2bf(d2); o.w = f2bf(d3);
            *(ushort4*)(h + (size_t)node * HID + t * 16 + lg * 4) = o;
        }
    }
#pragma unroll
    for (int i = 0; i < 16; ++i) {
        s1[i] += __shfl_xor(s1[i], 1, 64); s1[i] += __shfl_xor(s1[i], 2, 64);
        s1[i] += __shfl_xor(s1[i], 4, 64); s1[i] += __shfl_xor(s1[i], 8, 64);
        s2[i] += __shfl_xor(s2[i], 1, 64); s2[i] += __shfl_xor(s2[i], 2, 64);
        s2[i] += __shfl_xor(s2[i], 4, 64); s2[i] += __shfl_xor(s2[i], 8, 64);
    }
    if (lc == 0) {
#pragma unroll
        for (int t = 0; t < 4; ++t)
#pragma unroll
            for (int r = 0; r < 4; ++r) {
                red1[wv][t * 16 + lg * 4 + r] = s1[t * 4 + r];
                red2[wv][t * 16 + lg * 4 + r] = s2[t * 4 + r];
            }
    }
    __syncthreads();
    if (tid < 64)
        atomicAdd(&stats[tid], red1[0][tid] + red1[1][tid] + red1[2][tid] + red1[3][tid]);
    else if (tid < 128) {
        int c = tid - 64;
        atomicAdd(&stats[HID + c], red2[0][c] + red2[1][c] + red2[2][c] + red2[3][c]);
    }
}

// ------- mlp2 (MFMA, C^T): BN -> ReLU -> @W2+b2 -> ReLU; row-major -------
__global__ __launch_bounds__(256, 2) void k_mlp2(const ushort* __restrict__ wfb,
                                                 const float* __restrict__ b2,
                                                 const float* __restrict__ gamma,
                                                 const float* __restrict__ beta,
                                                 const float* __restrict__ stats,
                                                 const ushort* __restrict__ h,
                                                 ushort* __restrict__ xb_out,
                                                 float* __restrict__ f_out,
                                                 int write_f32) {
    int tid = threadIdx.x, wv = tid >> 6, l = tid & 63;
    int lg = l >> 4, lc = l & 15;
    short8 bhi[2][4], blo[2][4];
#pragma unroll
    for (int kh = 0; kh < 2; ++kh)
#pragma unroll
        for (int t = 0; t < 4; ++t) {
            bhi[kh][t] = *(const short8*)(wfb + 8192 + ((kh * 4 + t) * 64 + l) * 8);
            blo[kh][t] = *(const short8*)(wfb + 12288 + ((kh * 4 + t) * 64 + l) * 8);
        }
    f32x4 bias4[4];
#pragma unroll
    for (int t = 0; t < 4; ++t) {
        float4 bv = *(const float4*)(b2 + t * 16 + lg * 4);
        bias4[t] = (f32x4){bv.x, bv.y, bv.z, bv.w};
    }
    float aCk[2][8], bCk[2][8];
#pragma unroll
    for (int kh = 0; kh < 2; ++kh)
#pragma unroll
        for (int j = 0; j < 8; ++j) {
            int k = kh * 32 + lg * 8 + j;
            float mu = stats[k] * (1.0f / NN);
            float var = fmaxf(stats[HID + k] * (1.0f / NN) - mu * mu, 0.f);
            float aC = gamma[k] * rsqrtf(var + BN_EPS);
            aCk[kh][j] = aC;
            bCk[kh][j] = beta[k] - mu * aC;
        }
    int gw = blockIdx.x * 4 + wv, nw = gridDim.x * 4;
    for (int tile = gw; tile < NT; tile += nw) {
        int node = tile * 16 + lc;
        const ushort* hp = h + (size_t)node * HID + lg * 8;
        short8 a0r = *(const short8*)hp;
        short8 a1r = *(const short8*)(hp + 32);
        short8 a0, a1;
#pragma unroll
        for (int j = 0; j < 8; ++j) {
            float v0 = fmaxf(aCk[0][j] * bf2f((ushort)a0r[j]) + bCk[0][j], 0.f);
            float v1 = fmaxf(aCk[1][j] * bf2f((ushort)a1r[j]) + bCk[1][j], 0.f);
            a0[j] = (short)f2bf(v0);
            a1[j] = (short)f2bf(v1);
        }
        f32x4 acc[4];
#pragma unroll
        for (int t = 0; t < 4; ++t) {
            acc[t] = bias4[t];
            acc[t] = __builtin_amdgcn_mfma_f32_16x16x32_bf16(bhi[0][t], a0, acc[t], 0, 0, 0);
            acc[t] = __builtin_amdgcn_mfma_f32_16x16x32_bf16(bhi[1][t], a1, acc[t], 0, 0, 0);
            acc[t] = __builtin_amdgcn_mfma_f32_16x16x32_bf16(blo[0][t], a0, acc[t], 0, 0, 0);
            acc[t] = __builtin_amdgcn_mfma_f32_16x16x32_bf16(blo[1][t], a1, acc[t], 0, 0, 0);
        }
        if (write_f32) {
#pragma unroll
            for (int t = 0; t < 4; ++t) {
                float4 o4;
                o4.x = fmaxf(acc[t][0], 0.f); o4.y = fmaxf(acc[t][1], 0.f);
                o4.z = fmaxf(acc[t][2], 0.f); o4.w = fmaxf(acc[t][3], 0.f);
                *(float4*)(f_out + (size_t)node * HID + t * 16 + lg * 4) = o4;
            }
        } else {
#pragma unroll
            for (int t = 0; t < 4; ++t) {
                ushort4 o;
                o.x = f2bf(fmaxf(acc[t][0], 0.f)); o.y = f2bf(fmaxf(acc[t][1], 0.f));
                o.z = f2bf(fmaxf(acc[t][2], 0.f)); o.w = f2bf(fmaxf(acc[t][3], 0.f));
                *(ushort4*)(xb_out + (size_t)node * HID + t * 16 + lg * 4) = o;
            }
        }
    }
}

extern "C" void kernel_launch(void* const* d_in, const int* in_sizes, int n_in,
                              void* d_out, int out_size, void* d_ws, size_t ws_size,
                              hipStream_t stream) {
    const float* x_in  = (const float*)d_in[0];
    const int*   ei    = (const int*)d_in[1];
    const float* att   = (const float*)d_in[2];
    const float* W1    = (const float*)d_in[3];
    const float* b1    = (const float*)d_in[4];
    const float* gamma = (const float*)d_in[5];
    const float* beta  = (const float*)d_in[6];
    const float* W2    = (const float*)d_in[7];
    const float* b2    = (const float*)d_in[8];
    float* out = (float*)d_out;

    char* ws = (char*)d_ws;
    size_t off = 0;
    auto alloc = [&](size_t bytes) -> void* {
        void* p = ws + off;
        off += (bytes + 255) & ~(size_t)255;
        return p;
    };
    ushort* xb    = (ushort*)alloc((size_t)NN * HID * 2);   // row-major bf16 x
    ushort* aggb  = (ushort*)alloc((size_t)NN * HID * 2);
    ushort* hb    = (ushort*)alloc((size_t)NN * HID * 2);
    ushort* wf    = (ushort*)alloc((size_t)12 * 4096 * 2);  // W fragments hi/lo
    int*    ghist = (int*)alloc((size_t)NB * GP * 4);
    int*    boffB = (int*)alloc((size_t)(NB + 1) * 4);
    int*    gcur  = (int*)alloc((size_t)NB * GP * 4);
    int*    pcnt  = (int*)alloc((size_t)BIN_GRID * NB * 4); // per-block bucket counts
    int*    offs  = (int*)alloc((size_t)(NN + 1) * 4);
    int2*   evb   = (int2*)alloc((size_t)NE * 8);
    uint*   evc   = (uint*)alloc((size_t)NE * 4);           // src | att15<<17
    int*    dh    = (int*)alloc((size_t)256 * GP * 4);
    int*    dcur  = (int*)alloc((size_t)256 * GP * 4);
    int*    perm  = (int*)alloc((size_t)NN * 4);
    float*  stats = (float*)alloc(NL * 128 * 4);

    hipMemsetAsync(ghist, 0, (size_t)NB * GP * 4, stream);
    hipMemsetAsync(dh, 0, (size_t)256 * GP * 4, stream);
    hipMemsetAsync(stats, 0, NL * 128 * 4, stream);

    k_conv<<<(NN * HID / 4 + 255) / 256, 256, 0, stream>>>(x_in, xb);
    k_wpack<<<12, 64, 0, stream>>>(W1, W2, wf);
    k_histB<<<BIN_GRID, 1024, 0, stream>>>(ei + NE, ghist, pcnt);
    k_scanB<<<1, 1024, 0, stream>>>(ghist, boffB, gcur);
    k_binB<<<BIN_GRID, 1024, 0, stream>>>(ei, att, pcnt, gcur, evb);
    k_scatter2<<<NB, 256, 0, stream>>>(evb, boffB, offs, evc);
    k_dhist<<<DGRID, 1024, 0, stream>>>(offs, dh);
    k_dscan<<<1, 256, 0, stream>>>(dh, dcur);
    k_dplace<<<DGRID, 1024, 0, stream>>>(offs, dcur, perm);

    for (int l = 0; l < NL; ++l) {
        const ushort* wfb = wf + (size_t)l * 4 * 4096;
        k_gather<<<GBLK, 256, 0, stream>>>(xb, offs, evc, perm, aggb);
        k_mlp1<<<1024, 256, 0, stream>>>(aggb, wfb, b1 + l * HID, hb, stats + l * 128);
        k_mlp2<<<1024, 256, 0, stream>>>(wfb, b2 + l * HID,
                                         gamma + l * HID, beta + l * HID,
                                         stats + l * 128, hb,
                                         xb, out, (l == NL - 1) ? 1 : 0);
    }
}

// Round 17
// 327.956 us; speedup vs baseline: 1.5314x; 1.0544x over previous
//
#include <hip/hip_runtime.h>

#define NN 100000
#define NE 1600000
#define HID 64
#define NT (NN / 16)           // 16-node MFMA tiles
#define NL 3
#define BN_EPS 1e-5f
#define BSH 7
#define BNODES 128
#define NB 782                 // ceil(NN / BNODES)
#define GP 16                  // global counter pad (ints) -> 64 B/line
#define BIN_CHUNK 8192
#define BIN_GRID ((NE + BIN_CHUNK - 1) / BIN_CHUNK)
#define GBLK 3125              // gather: 12500 waves x 8 nodes = 100000
#define DCHUNK 8192
#define DGRID ((NN + DCHUNK - 1) / DCHUNK)

typedef __attribute__((ext_vector_type(8))) short short8;
typedef __attribute__((ext_vector_type(4))) float f32x4;

__device__ __forceinline__ float bf2f(unsigned short u) {
    union { unsigned int i; float f; } v; v.i = ((unsigned int)u) << 16; return v.f;
}
__device__ __forceinline__ unsigned short f2bf(float f) {
    union { float f; unsigned int i; } v; v.f = f;
    unsigned int r = v.i + 0x7FFFu + ((v.i >> 16) & 1u);   // RNE
    return (unsigned short)(r >> 16);
}
__device__ __forceinline__ float lof(uint r) {
    union { uint u; float f; } v; v.u = r << 16; return v.f;
}
__device__ __forceinline__ float hif(uint r) {
    union { uint u; float f; } v; v.u = r & 0xFFFF0000u; return v.f;
}

// ---------------- input convert x f32 -> bf16 row-major ----------------
__global__ void k_conv(const float* __restrict__ x, ushort* __restrict__ xb) {
    int i = blockIdx.x * blockDim.x + threadIdx.x;   // over NN*HID/4
    float4 v = ((const float4*)x)[i];
    ushort4 o;
    o.x = f2bf(v.x); o.y = f2bf(v.y); o.z = f2bf(v.z); o.w = f2bf(v.w);
    ((ushort4*)xb)[i] = o;
}

// ---------------- pack W1/W2 into hi/lo bf16 MFMA fragments ----------------
__global__ void k_wpack(const float* __restrict__ W1, const float* __restrict__ W2,
                        ushort* __restrict__ wf) {
    int s = blockIdx.x, l = threadIdx.x;
    int layer = s >> 2, kind = s & 3;
    const float* W = ((kind < 2) ? W1 : W2) + (size_t)layer * HID * HID;
    ushort* o = wf + (size_t)s * 4096;
    for (int kh = 0; kh < 2; ++kh)
        for (int t = 0; t < 4; ++t)
            for (int j = 0; j < 8; ++j) {
                int k = kh * 32 + (l >> 4) * 8 + j;
                int n = t * 16 + (l & 15);
                float f = W[k * HID + n];
                ushort hi = f2bf(f);
                o[((kh * 4 + t) * 64 + l) * 8 + j] =
                    (kind & 1) ? f2bf(f - bf2f(hi)) : hi;
            }
}

// ------- bucket histogram: 1024 thr, int4 batch; saves per-block counts -------
__global__ __launch_bounds__(1024) void k_histB(const int* __restrict__ dst,
                                                int* __restrict__ ghist,
                                                int* __restrict__ pcnt) {
    __shared__ int lh[NB];
    int tid = threadIdx.x;
    for (int i = tid; i < NB; i += 1024) lh[i] = 0;
    __syncthreads();
    int base = blockIdx.x * BIN_CHUNK;
    int end = min(base + BIN_CHUNK, NE);
    for (int e = base + tid * 4; e + 3 < end; e += 4096) {
        int4 d = *(const int4*)(dst + e);
        atomicAdd(&lh[d.x >> BSH], 1);
        atomicAdd(&lh[d.y >> BSH], 1);
        atomicAdd(&lh[d.z >> BSH], 1);
        atomicAdd(&lh[d.w >> BSH], 1);
    }
    __syncthreads();
    int* prow = pcnt + (size_t)blockIdx.x * NB;
    for (int i = tid; i < NB; i += 1024) {
        int c = lh[i];
        prow[i] = c;                                  // coalesced save for binB
        if (c) atomicAdd(&ghist[i * GP], c);
    }
}

// ---------------- bucket scan (one block, NB <= 1024) ----------------
__global__ void k_scanB(const int* __restrict__ ghist, int* __restrict__ boffB,
                        int* __restrict__ gcur) {
    __shared__ int t[1024];
    int tid = threadIdx.x;
    int v = (tid < NB) ? ghist[tid * GP] : 0;
    t[tid] = v;
    __syncthreads();
    for (int d = 1; d < 1024; d <<= 1) {
        int u = (tid >= d) ? t[tid - d] : 0;
        __syncthreads();
        t[tid] += u;
        __syncthreads();
    }
    if (tid < NB) { int ex = t[tid] - v; boffB[tid] = ex; gcur[tid * GP] = ex; }
    if (tid == 0) boffB[NB] = NE;
}

// ------- binning: reuses pcnt (no re-hist), bulk reserve, 4-edge batch -------
__global__ __launch_bounds__(1024) void k_binB(const int* __restrict__ ei,
                                               const float* __restrict__ att,
                                               const int* __restrict__ pcnt,
                                               int* __restrict__ gcur,
                                               int2* __restrict__ evb) {
    __shared__ int lh[NB];
    int tid = threadIdx.x;
    const int* prow = pcnt + (size_t)blockIdx.x * NB;
    for (int i = tid; i < NB; i += 1024) {
        int c = prow[i];
        lh[i] = c ? atomicAdd(&gcur[i * GP], c) : 0;   // lh becomes running cursor
    }
    __syncthreads();
    int base = blockIdx.x * BIN_CHUNK;
    int end = min(base + BIN_CHUNK, NE);
    for (int e = base + tid * 4; e + 3 < end; e += 4096) {
        int4 s = *(const int4*)(ei + e);
        int4 d = *(const int4*)(ei + NE + e);
        float4 a = *(const float4*)(att + e);
        int p0 = atomicAdd(&lh[d.x >> BSH], 1);
        int p1 = atomicAdd(&lh[d.y >> BSH], 1);
        int p2 = atomicAdd(&lh[d.z >> BSH], 1);
        int p3 = atomicAdd(&lh[d.w >> BSH], 1);
        evb[p0] = make_int2(s.x | ((d.x & (BNODES - 1)) << 17), __float_as_int(a.x));
        evb[p1] = make_int2(s.y | ((d.y & (BNODES - 1)) << 17), __float_as_int(a.y));
        evb[p2] = make_int2(s.z | ((d.z & (BNODES - 1)) << 17), __float_as_int(a.z));
        evb[p3] = make_int2(s.w | ((d.w & (BNODES - 1)) << 17), __float_as_int(a.w));
    }
}

// ------- pass 2: per-bucket CSR placement; compressed 4 B records -------
__global__ __launch_bounds__(256) void k_scatter2(const int2* __restrict__ evb,
                                                  const int* __restrict__ boffB,
                                                  int* __restrict__ offs,
                                                  uint* __restrict__ evc) {
    __shared__ int h[BNODES];
    __shared__ int cur[BNODES];
    int tid = threadIdx.x;
    int b = blockIdx.x;
    int node0 = b << BSH;
    int nvalid = min(BNODES, NN - node0);
    int e0 = boffB[b], e1 = boffB[b + 1];
    if (tid < BNODES) h[tid] = 0;
    __syncthreads();
    for (int e = e0 + tid * 2; e < e1; e += 512) {
        int2 r0 = evb[e];
        int v1 = (e + 1 < e1);
        int2 r1 = evb[v1 ? e + 1 : e];
        atomicAdd(&h[r0.x >> 17], 1);
        if (v1) atomicAdd(&h[r1.x >> 17], 1);
    }
    __syncthreads();
    int v = (tid < BNODES) ? h[tid] : 0;
    for (int d = 1; d < BNODES; d <<= 1) {
        int u = (tid >= d && tid < BNODES) ? h[tid - d] : 0;
        __syncthreads();
        if (tid < BNODES) h[tid] += u;
        __syncthreads();
    }
    if (tid < BNODES) {
        int start = e0 + h[tid] - v;
        cur[tid] = start;
        if (tid < nvalid) offs[node0 + tid] = start;
    }
    if (b == NB - 1 && tid == 0) offs[NN] = NE;
    __syncthreads();
    for (int e = e0 + tid * 2; e < e1; e += 512) {
        int2 r0 = evb[e];
        int v1 = (e + 1 < e1);
        int2 r1 = evb[v1 ? e + 1 : e];
        int p0 = atomicAdd(&cur[r0.x >> 17], 1);
        int p1 = v1 ? atomicAdd(&cur[r1.x >> 17], 1) : 0;
        uint a0 = (uint)(__int_as_float(r0.y) * 32767.0f + 0.5f);
        evc[p0] = ((uint)r0.x & 0x1FFFFu) | (a0 << 17);
        if (v1) {
            uint a1 = (uint)(__int_as_float(r1.y) * 32767.0f + 0.5f);
            evc[p1] = ((uint)r1.x & 0x1FFFFu) | (a1 << 17);
        }
    }
}

// ------- degree sort: hist (LDS pre-aggregated) -> scan -> place -------
__global__ __launch_bounds__(1024) void k_dhist(const int* __restrict__ offs,
                                                int* __restrict__ dh) {
    __shared__ int lh[256];
    int tid = threadIdx.x;
    if (tid < 256) lh[tid] = 0;
    __syncthreads();
    int lo = blockIdx.x * DCHUNK, hi = min(lo + DCHUNK, NN);
    for (int i = lo + tid; i < hi; i += 1024)
        atomicAdd(&lh[min(offs[i + 1] - offs[i], 255)], 1);
    __syncthreads();
    if (tid < 256 && lh[tid]) atomicAdd(&dh[tid * GP], lh[tid]);
}

__global__ void k_dscan(const int* __restrict__ dh, int* __restrict__ dcur) {
    __shared__ int t[256];
    int tid = threadIdx.x;
    int v = dh[tid * GP];
    t[tid] = v;
    __syncthreads();
    for (int d = 1; d < 256; d <<= 1) {
        int u = (tid >= d) ? t[tid - d] : 0;
        __syncthreads();
        t[tid] += u;
        __syncthreads();
    }
    dcur[tid * GP] = t[tid] - v;
}

__global__ __launch_bounds__(1024) void k_dplace(const int* __restrict__ offs,
                                                 int* __restrict__ dcur,
                                                 int* __restrict__ perm) {
    __shared__ int lh[256];
    __shared__ int lbase[256];
    int tid = threadIdx.x;
    if (tid < 256) lh[tid] = 0;
    __syncthreads();
    int lo = blockIdx.x * DCHUNK, hi = min(lo + DCHUNK, NN);
    int mybin[8], myrk[8];
#pragma unroll 8
    for (int u = 0; u < 8; ++u) {
        int i = lo + u * 1024 + tid;
        if (i < hi) {
            int b = min(offs[i + 1] - offs[i], 255);
            mybin[u] = b;
            myrk[u] = atomicAdd(&lh[b], 1);
        } else mybin[u] = -1;
    }
    __syncthreads();
    if (tid < 256) {
        int c = lh[tid];
        lbase[tid] = c ? atomicAdd(&dcur[tid * GP], c) : 0;
    }
    __syncthreads();
#pragma unroll 8
    for (int u = 0; u < 8; ++u) {
        int i = lo + u * 1024 + tid;
        if (mybin[u] >= 0) perm[lbase[mybin[u]] + myrk[u]] = i;
    }
}

// ------- gather: 8 nodes/wave, uint4 rows, 3-phase unrolled ILP, 16 waves/CU -------
__global__ __launch_bounds__(256, 4) void k_gather(const ushort* __restrict__ xb,
                                                   const int* __restrict__ offs,
                                                   const uint* __restrict__ evc,
                                                   const int* __restrict__ perm,
                                                   ushort* __restrict__ agg) {
    int tid = threadIdx.x;
    int wid = blockIdx.x * 4 + (tid >> 6);
    int lane = tid & 63;
    int g = lane >> 3, k = lane & 7;
    const uint4* xq4 = (const uint4*)xb;
    uint4* aq4 = (uint4*)agg;
    int node = perm[wid * 8 + g];
    int e0 = offs[node], e1 = offs[node + 1];
    int deg = e1 - e0;
    uint4 s4 = xq4[(size_t)node * 8 + k];                 // self row (+x, eps=0)
    float ax0 = lof(s4.x), ay0 = hif(s4.x);
    float ax1 = lof(s4.y), ay1 = hif(s4.y);
    float ax2 = lof(s4.z), ay2 = hif(s4.z);
    float ax3 = lof(s4.w), ay3 = hif(s4.w);
    int maxd = deg;                                        // max degree over 8 groups
    maxd = max(maxd, __shfl_xor(maxd, 8, 64));
    maxd = max(maxd, __shfl_xor(maxd, 16, 64));
    maxd = max(maxd, __shfl_xor(maxd, 32, 64));
    uint ew = evc[min(e0 + k, NE - 1)];                   // first metadata batch
    for (int base = 0; base < maxd; base += 8) {
        uint ewc = ew;
        if (base + 8 < maxd) ew = evc[min(e0 + base + 8 + k, NE - 1)];  // hoisted
        // phase 1: broadcast 8 edges' metadata to the group
        uint w[8]; float a[8];
#pragma unroll
        for (int j = 0; j < 8; ++j) {
            w[j] = (uint)__builtin_amdgcn_ds_bpermute((g * 8 + j) << 2, (int)ewc);
            a[j] = (base + j < deg) ? (float)(w[j] >> 17) * (1.0f / 32767.0f) : 0.f;
        }
        // phase 2: issue all 8 row loads back-to-back (8 x 128 B in flight)
        uint4 r[8];
#pragma unroll
        for (int j = 0; j < 8; ++j)
            r[j] = xq4[(size_t)(w[j] & 0x1FFFF) * 8 + k];
        // phase 3: accumulate
#pragma unroll
        for (int j = 0; j < 8; ++j) {
            ax0 += lof(r[j].x) * a[j]; ay0 += hif(r[j].x) * a[j];
            ax1 += lof(r[j].y) * a[j]; ay1 += hif(r[j].y) * a[j];
            ax2 += lof(r[j].z) * a[j]; ay2 += hif(r[j].z) * a[j];
            ax3 += lof(r[j].w) * a[j]; ay3 += hif(r[j].w) * a[j];
        }
    }
    uint4 o;
    o.x = ((uint)f2bf(ax0)) | (((uint)f2bf(ay0)) << 16);
    o.y = ((uint)f2bf(ax1)) | (((uint)f2bf(ay1)) << 16);
    o.z = ((uint)f2bf(ax2)) | (((uint)f2bf(ay2)) << 16);
    o.w = ((uint)f2bf(ax3)) | (((uint)f2bf(ay3)) << 16);
    aq4[(size_t)node * 8 + k] = o;
}

// ------- mlp1 (MFMA, C^T): h = agg @ W1 + b1, BN stats; row-major -------
__global__ __launch_bounds__(256, 2) void k_mlp1(const ushort* __restrict__ aggc,
                                                 const ushort* __restrict__ wfb,
                                                 const float* __restrict__ b1,
                                                 ushort* __restrict__ h,
                                                 float* __restrict__ stats) {
    __shared__ float red1[4][64], red2[4][64];
    int tid = threadIdx.x, wv = tid >> 6, l = tid & 63;
    int lg = l >> 4, lc = l & 15;
    short8 bhi[2][4], blo[2][4];
#pragma unroll
    for (int kh = 0; kh < 2; ++kh)
#pragma unroll
        for (int t = 0; t < 4; ++t) {
            bhi[kh][t] = *(const short8*)(wfb + ((kh * 4 + t) * 64 + l) * 8);
            blo[kh][t] = *(const short8*)(wfb + 4096 + ((kh * 4 + t) * 64 + l) * 8);
        }
    f32x4 bias4[4];
#pragma unroll
    for (int t = 0; t < 4; ++t) {
        float4 bv = *(const float4*)(b1 + t * 16 + lg * 4);
        bias4[t] = (f32x4){bv.x, bv.y, bv.z, bv.w};
    }
    float s1[16], s2[16];
#pragma unroll
    for (int i = 0; i < 16; ++i) { s1[i] = 0.f; s2[i] = 0.f; }
    int gw = blockIdx.x * 4 + wv, nw = gridDim.x * 4;
    for (int tile = gw; tile < NT; tile += nw) {
        int node = tile * 16 + lc;
        const ushort* ap = aggc + (size_t)node * HID + lg * 8;
        short8 a0 = *(const short8*)ap;             // k = 0..31
        short8 a1 = *(const short8*)(ap + 32);      // k = 32..63
        f32x4 acc[4];
#pragma unroll
        for (int t = 0; t < 4; ++t) {
            acc[t] = bias4[t];
            acc[t] = __builtin_amdgcn_mfma_f32_16x16x32_bf16(bhi[0][t], a0, acc[t], 0, 0, 0);
            acc[t] = __builtin_amdgcn_mfma_f32_16x16x32_bf16(bhi[1][t], a1, acc[t], 0, 0, 0);
            acc[t] = __builtin_amdgcn_mfma_f32_16x16x32_bf16(blo[0][t], a0, acc[t], 0, 0, 0);
            acc[t] = __builtin_amdgcn_mfma_f32_16x16x32_bf16(blo[1][t], a1, acc[t], 0, 0, 0);
        }
#pragma unroll
        for (int t = 0; t < 4; ++t) {
            ushort4 o;
            float d0 = acc[t][0], d1 = acc[t][1], d2 = acc[t][2], d3 = acc[t][3];
            s1[t * 4 + 0] += d0; s2[t * 4 + 0] += d0 * d0;
            s1[t * 4 + 1] += d1; s2[t * 4 + 1] += d1 * d1;
            s1[t * 4 + 2] += d2; s2[t * 4 + 2] += d2 * d2;
            s1[t * 4 + 3] += d3; s2[t * 4 + 3] += d3 * d3;
            o.x = f2bf(d0); o.y = f2bf(d1); o.z = f2bf(d2); o.w = f2bf(d3);
            *(ushort4*)(h + (size_t)node * HID + t * 16 + lg * 4) = o;
        }
    }
#pragma unroll
    for (int i = 0; i < 16; ++i) {
        s1[i] += __shfl_xor(s1[i], 1, 64); s1[i] += __shfl_xor(s1[i], 2, 64);
        s1[i] += __shfl_xor(s1[i], 4, 64); s1[i] += __shfl_xor(s1[i], 8, 64);
        s2[i] += __shfl_xor(s2[i], 1, 64); s2[i] += __shfl_xor(s2[i], 2, 64);
        s2[i] += __shfl_xor(s2[i], 4, 64); s2[i] += __shfl_xor(s2[i], 8, 64);
    }
    if (lc == 0) {
#pragma unroll
        for (int t = 0; t < 4; ++t)
#pragma unroll
            for (int r = 0; r < 4; ++r) {
                red1[wv][t * 16 + lg * 4 + r] = s1[t * 4 + r];
                red2[wv][t * 16 + lg * 4 + r] = s2[t * 4 + r];
            }
    }
    __syncthreads();
    if (tid < 64)
        atomicAdd(&stats[tid], red1[0][tid] + red1[1][tid] + red1[2][tid] + red1[3][tid]);
    else if (tid < 128) {
        int c = tid - 64;
        atomicAdd(&stats[HID + c], red2[0][c] + red2[1][c] + red2[2][c] + red2[3][c]);
    }
}

// ------- mlp2 (MFMA, C^T): BN -> ReLU -> @W2+b2 -> ReLU; row-major -------
__global__ __launch_bounds__(256, 2) void k_mlp2(const ushort* __restrict__ wfb,
                                                 const float* __restrict__ b2,
                                                 const float* __restrict__ gamma,
                                                 const float* __restrict__ beta,
                                                 const float* __restrict__ stats,
                                                 const ushort* __restrict__ h,
                                                 ushort* __restrict__ xb_out,
                                                 float* __restrict__ f_out,
                                                 int write_f32) {
    int tid = threadIdx.x, wv = tid >> 6, l = tid & 63;
    int lg = l >> 4, lc = l & 15;
    short8 bhi[2][4], blo[2][4];
#pragma unroll
    for (int kh = 0; kh < 2; ++kh)
#pragma unroll
        for (int t = 0; t < 4; ++t) {
            bhi[kh][t] = *(const short8*)(wfb + 8192 + ((kh * 4 + t) * 64 + l) * 8);
            blo[kh][t] = *(const short8*)(wfb + 12288 + ((kh * 4 + t) * 64 + l) * 8);
        }
    f32x4 bias4[4];
#pragma unroll
    for (int t = 0; t < 4; ++t) {
        float4 bv = *(const float4*)(b2 + t * 16 + lg * 4);
        bias4[t] = (f32x4){bv.x, bv.y, bv.z, bv.w};
    }
    float aCk[2][8], bCk[2][8];
#pragma unroll
    for (int kh = 0; kh < 2; ++kh)
#pragma unroll
        for (int j = 0; j < 8; ++j) {
            int k = kh * 32 + lg * 8 + j;
            float mu = stats[k] * (1.0f / NN);
            float var = fmaxf(stats[HID + k] * (1.0f / NN) - mu * mu, 0.f);
            float aC = gamma[k] * rsqrtf(var + BN_EPS);
            aCk[kh][j] = aC;
            bCk[kh][j] = beta[k] - mu * aC;
        }
    int gw = blockIdx.x * 4 + wv, nw = gridDim.x * 4;
    for (int tile = gw; tile < NT; tile += nw) {
        int node = tile * 16 + lc;
        const ushort* hp = h + (size_t)node * HID + lg * 8;
        short8 a0r = *(const short8*)hp;
        short8 a1r = *(const short8*)(hp + 32);
        short8 a0, a1;
#pragma unroll
        for (int j = 0; j < 8; ++j) {
            float v0 = fmaxf(aCk[0][j] * bf2f((ushort)a0r[j]) + bCk[0][j], 0.f);
            float v1 = fmaxf(aCk[1][j] * bf2f((ushort)a1r[j]) + bCk[1][j], 0.f);
            a0[j] = (short)f2bf(v0);
            a1[j] = (short)f2bf(v1);
        }
        f32x4 acc[4];
#pragma unroll
        for (int t = 0; t < 4; ++t) {
            acc[t] = bias4[t];
            acc[t] = __builtin_amdgcn_mfma_f32_16x16x32_bf16(bhi[0][t], a0, acc[t], 0, 0, 0);
            acc[t] = __builtin_amdgcn_mfma_f32_16x16x32_bf16(bhi[1][t], a1, acc[t], 0, 0, 0);
            acc[t] = __builtin_amdgcn_mfma_f32_16x16x32_bf16(blo[0][t], a0, acc[t], 0, 0, 0);
            acc[t] = __builtin_amdgcn_mfma_f32_16x16x32_bf16(blo[1][t], a1, acc[t], 0, 0, 0);
        }
        if (write_f32) {
#pragma unroll
            for (int t = 0; t < 4; ++t) {
                float4 o4;
                o4.x = fmaxf(acc[t][0], 0.f); o4.y = fmaxf(acc[t][1], 0.f);
                o4.z = fmaxf(acc[t][2], 0.f); o4.w = fmaxf(acc[t][3], 0.f);
                *(float4*)(f_out + (size_t)node * HID + t * 16 + lg * 4) = o4;
            }
        } else {
#pragma unroll
            for (int t = 0; t < 4; ++t) {
                ushort4 o;
                o.x = f2bf(fmaxf(acc[t][0], 0.f)); o.y = f2bf(fmaxf(acc[t][1], 0.f));
                o.z = f2bf(fmaxf(acc[t][2], 0.f)); o.w = f2bf(fmaxf(acc[t][3], 0.f));
                *(ushort4*)(xb_out + (size_t)node * HID + t * 16 + lg * 4) = o;
            }
        }
    }
}

extern "C" void kernel_launch(void* const* d_in, const int* in_sizes, int n_in,
                              void* d_out, int out_size, void* d_ws, size_t ws_size,
                              hipStream_t stream) {
    const float* x_in  = (const float*)d_in[0];
    const int*   ei    = (const int*)d_in[1];
    const float* att   = (const float*)d_in[2];
    const float* W1    = (const float*)d_in[3];
    const float* b1    = (const float*)d_in[4];
    const float* gamma = (const float*)d_in[5];
    const float* beta  = (const float*)d_in[6];
    const float* W2    = (const float*)d_in[7];
    const float* b2    = (const float*)d_in[8];
    float* out = (float*)d_out;

    char* ws = (char*)d_ws;
    size_t off = 0;
    auto alloc = [&](size_t bytes) -> void* {
        void* p = ws + off;
        off += (bytes + 255) & ~(size_t)255;
        return p;
    };
    ushort* xb    = (ushort*)alloc((size_t)NN * HID * 2);   // row-major bf16 x
    ushort* aggb  = (ushort*)alloc((size_t)NN * HID * 2);
    ushort* hb    = (ushort*)alloc((size_t)NN * HID * 2);
    ushort* wf    = (ushort*)alloc((size_t)12 * 4096 * 2);  // W fragments hi/lo
    int*    ghist = (int*)alloc((size_t)NB * GP * 4);
    int*    boffB = (int*)alloc((size_t)(NB + 1) * 4);
    int*    gcur  = (int*)alloc((size_t)NB * GP * 4);
    int*    pcnt  = (int*)alloc((size_t)BIN_GRID * NB * 4); // per-block bucket counts
    int*    offs  = (int*)alloc((size_t)(NN + 1) * 4);
    int2*   evb   = (int2*)alloc((size_t)NE * 8);
    uint*   evc   = (uint*)alloc((size_t)NE * 4);           // src | att15<<17
    int*    dh    = (int*)alloc((size_t)256 * GP * 4);
    int*    dcur  = (int*)alloc((size_t)256 * GP * 4);
    int*    perm  = (int*)alloc((size_t)NN * 4);
    float*  stats = (float*)alloc(NL * 128 * 4);

    hipMemsetAsync(ghist, 0, (size_t)NB * GP * 4, stream);
    hipMemsetAsync(dh, 0, (size_t)256 * GP * 4, stream);
    hipMemsetAsync(stats, 0, NL * 128 * 4, stream);

    k_conv<<<(NN * HID / 4 + 255) / 256, 256, 0, stream>>>(x_in, xb);
    k_wpack<<<12, 64, 0, stream>>>(W1, W2, wf);
    k_histB<<<BIN_GRID, 1024, 0, stream>>>(ei + NE, ghist, pcnt);
    k_scanB<<<1, 1024, 0, stream>>>(ghist, boffB, gcur);
    k_binB<<<BIN_GRID, 1024, 0, stream>>>(ei, att, pcnt, gcur, evb);
    k_scatter2<<<NB, 256, 0, stream>>>(evb, boffB, offs, evc);
    k_dhist<<<DGRID, 1024, 0, stream>>>(offs, dh);
    k_dscan<<<1, 256, 0, stream>>>(dh, dcur);
    k_dplace<<<DGRID, 1024, 0, stream>>>(offs, dcur, perm);

    for (int l = 0; l < NL; ++l) {
        const ushort* wfb = wf + (size_t)l * 4 * 4096;
        k_gather<<<GBLK, 256, 0, stream>>>(xb, offs, evc, perm, aggb);
        k_mlp1<<<1024, 256, 0, stream>>>(aggb, wfb, b1 + l * HID, hb, stats + l * 128);
        k_mlp2<<<1024, 256, 0, stream>>>(wfb, b2 + l * HID,
                                         gamma + l * HID, beta + l * HID,
                                         stats + l * 128, hb,
                                         xb, out, (l == NL - 1) ? 1 : 0);
    }
}